// Round 10
// baseline (97.461 us; speedup 1.0000x reference)
//
#include <hip/hip_runtime.h>

// Problem constants
#define NB 4      // batch
#define NI 160    // input spatial size (all 3 dims)
#define NO 43     // output spatial size: ceil(160/4)+3
#define NC 3      // channels
#define KS 7      // gaussian kernel size per axis
#define KPAD 3    // (KS-1)/2
#define MT 16     // stored taps per banded row (true max = 14)
#define CH 8      // rows per chunk (fallback)

#define ROWF (NI * NC)            // 480 floats per input row
#define PROW 132                  // padded (o3,c) row: 129 -> 132 floats
#define PROW4 (PROW / 4)          // 33 float4
#define LROW 484                  // LDS row stride (484 % 32 == 4 -> <=8 rows alias-free)
#define SLICE (NO * NO * NC)

#define A2_BYTES ((size_t)NB * NI * NO * PROW * 4)       // 14,530,560
#define P3_THREADS ((size_t)NB * NO * NO * PROW4)        // 244,068

// ===========================================================================
// Compile-time weight tables (validated r8/r9, absmax 4.88e-4).
// ===========================================================================
struct __align__(16) Tables {
    float wa3[NO][20];   // aligned 20-float composite windows (i3 contraction)
    float w1[NO][MT];    // banded 16-tap composite weights (shared by axes)
    int   o0[NO][MT];    // clamped byte offsets, stride NO*PROW*4 = 22704 (p3)
    int   j3[NO];        // aligned window starts (multiples of 4)
    int   jlo[NO];       // band starts
};

constexpr double ctaylor(double r) {            // exp(r), r in [0, 1/16]
    double s = 1.0, term = 1.0;
    for (int n = 1; n <= 13; ++n) { term *= r / (double)n; s += term; }
    return s;
}
constexpr double cexp_neg(double x) {           // exp(x), x <= 0, |x| < 40
    double y = -x;
    int k = (int)(y * 16.0);
    double r = y - (double)k / 16.0;
    double e16 = ctaylor(1.0 / 16.0);
    double p = 1.0;
    for (int i = 0; i < k; ++i) p *= e16;
    return 1.0 / (p * ctaylor(r));
}
constexpr int cceil(double x)  { int c = (int)x; return ((double)c < x) ? c + 1 : c; }
constexpr int cfloor(double x) { int f = (int)x; return ((double)f > x) ? f - 1 : f; }
constexpr double cabsd(double x) { return x < 0 ? -x : x; }

constexpr double comp_w(int j, double sf, int ilo, int ihi, const double* g) {
    if (j >= NI || j < 0) return 0.0;           // taps at j>=NI are exactly 0
    double cw = 0.0;
    for (int t = 0; t < KS; ++t) {
        int i = j + KPAD - t;
        if (i >= ilo && i <= ihi) {
            double w = 1.0 - cabsd(sf - (double)i) * (43.0 / 160.0);
            if (w > 0.0) cw += g[t] * w;
        }
    }
    return cw;
}

constexpr Tables make_tables() {
    Tables T{};
    double g[KS] = {};
    double gs = 0.0;
    const double sig = 0.44 * 4.0;
    for (int i = 0; i < KS; ++i) {
        double d = (double)i - 3.0;
        g[i] = cexp_neg(-(d * d) / (2.0 * sig * sig));
        gs += g[i];
    }
    for (int i = 0; i < KS; ++i) g[i] /= gs;

    const double inv_scale = 160.0 / 43.0;
    for (int o = 0; o < NO; ++o) {
        double sf = ((double)o + 0.5) * inv_scale - 0.5;
        int ilo = cceil(sf - inv_scale);  if (ilo < 0) ilo = 0;
        int ihi = cfloor(sf + inv_scale); if (ihi > NI - 1) ihi = NI - 1;
        double wsum = 0.0;
        for (int i = ilo; i <= ihi; ++i) {
            double w = 1.0 - cabsd(sf - (double)i) * (43.0 / 160.0);
            if (w > 0.0) wsum += w;
        }
        int jlo = ilo - KPAD; if (jlo < 0) jlo = 0;
        int j0 = jlo & ~3;
        T.j3[o] = j0;
        T.jlo[o] = jlo;
        for (int m = 0; m < 20; ++m)
            T.wa3[o][m] = (float)(comp_w(j0 + m, sf, ilo, ihi, g) / wsum);
        for (int k = 0; k < MT; ++k) {
            int j = jlo + k;
            T.w1[o][k] = (float)(comp_w(j, sf, ilo, ihi, g) / wsum);
            int jc = (j < NI) ? j : (NI - 1);
            T.o0[o][k] = jc * (NO * PROW * 4);
        }
    }
    return T;
}

__constant__ Tables dT = make_tables();

// ===========================================================================
// FUSED v2: contract i3 AND i2. Block = (slab, o2-half): 1280 blocks,
// 256 threads, ~26 KB LDS -> 4-6 blocks/CU. 8-row chunks (alias-free in LDS),
// single tc buffer, 2 barriers/chunk; stage(next) overlaps acc phase.
// Output A2[b][i1][o2][132] directly (A1 round-trip eliminated).
// ===========================================================================
__global__ __launch_bounds__(256, 4) void k_f2(
        const float* __restrict__ img, float* __restrict__ A2) {
    __shared__ __align__(16) float raw[8 * LROW + 64];   // 15.7 KB
    __shared__ __align__(16) float tc[8 * PROW];         // 4.2 KB
    __shared__ __align__(16) float swa[NO * 20];         // 3.4 KB
    __shared__ __align__(16) float sw1[NO * MT];         // 2.8 KB
    __shared__ int sj0[NO], sjlo[NO];
    const int t = threadIdx.x;
    const int blk = blockIdx.x;                 // 0..1279
    const int slab = blk >> 1;                  // b*160 + i1
    const int half = blk & 1;
    const int o2a = half ? 22 : 0;
    const int o2n = half ? 21 : 22;

    const float4* src4 = (const float4*)(img + (size_t)slab * (NI * ROWF));

    // tables -> LDS; zero pads
    for (int k = t; k < NO * 20; k += 256) swa[k] = ((const float*)dT.wa3)[k];
    for (int k = t; k < NO * MT; k += 256) sw1[k] = ((const float*)dT.w1)[k];
    if (t < NO) { sj0[t] = dT.j3[t]; sjlo[t] = dT.jlo[t]; }
    if (t < 32) raw[(t >> 2) * LROW + ROWF + (t & 3)] = 0.f;       // row pads
    if (t >= 32 && t < 96) raw[8 * LROW + (t - 32)] = 0.f;         // tail slack
    if (t >= 96 && t < 120) {                                      // tc col pads
        int q = t - 96;
        tc[(q / 3) * PROW + NO * NC + (q % 3)] = 0.f;
    }

    const int r0 = dT.jlo[o2a];
    int r1 = dT.jlo[o2a + o2n - 1] + MT; if (r1 > NI) r1 = NI;
    const int nc = (r1 - r0 + 7) >> 3;

    // per-thread accumulators over (o2local*33 + col4), o2n*33 <= 726
    float4 acc0 = {0.f,0.f,0.f,0.f}, acc1 = acc0, acc2 = acc0;
    const int lim = o2n * PROW4;
    const int idx0 = t, idx1 = t + 256, idx2 = t + 512;
    const int o2_0 = o2a + idx0 / PROW4, c4_0 = idx0 % PROW4;
    const int o2_1 = o2a + idx1 / PROW4, c4_1 = idx1 % PROW4;
    const int o2_2 = (idx2 < lim) ? (o2a + idx2 / PROW4) : o2a;
    const int c4_2 = idx2 % PROW4;

    // stage chunk 0 (rows r0..r0+7, clamped)
    for (int g = t; g < 960; g += 256) {
        int row = g / 120, m = g % 120;
        int grow = r0 + row; grow = (grow < NI) ? grow : (NI - 1);
        *(float4*)(raw + row * LROW + 4 * m) = src4[(size_t)grow * 120 + m];
    }
    __syncthreads();

    for (int c = 0; c < nc; ++c) {
        const int cs = r0 + 8 * c;
        // ---- contract i3: 8 rows x 43 o3 -> tc ----
        for (int task = t; task < 8 * NO; task += 256) {
            int row = task & 7, o3 = task >> 3;
            int j0 = sj0[o3];
            const float4* dp = (const float4*)(raw + row * LROW + 3 * j0);
            const float4* wp = (const float4*)(swa + o3 * 20);
            float a0 = 0.f, a1 = 0.f, a2 = 0.f;
            #pragma unroll
            for (int m = 0; m < 5; ++m) {
                float4 w4 = wp[m];
                float4 v0 = dp[3 * m], v1 = dp[3 * m + 1], v2 = dp[3 * m + 2];
                a0 += w4.x * v0.x; a1 += w4.x * v0.y; a2 += w4.x * v0.z;
                a0 += w4.y * v0.w; a1 += w4.y * v1.x; a2 += w4.y * v1.y;
                a0 += w4.z * v1.z; a1 += w4.z * v1.w; a2 += w4.z * v2.x;
                a0 += w4.w * v2.y; a1 += w4.w * v2.z; a2 += w4.w * v2.w;
            }
            float* op = tc + row * PROW + o3 * 3;
            op[0] = a0; op[1] = a1; op[2] = a2;
        }
        __syncthreads();                 // tc ready; raw free to overwrite

        // ---- stage next chunk (overlaps acc phase; acc reads only tc) ----
        if (c + 1 < nc) {
            const int ns = cs + 8;
            for (int g = t; g < 960; g += 256) {
                int row = g / 120, m = g % 120;
                int grow = ns + row; grow = (grow < NI) ? grow : (NI - 1);
                *(float4*)(raw + row * LROW + 4 * m) = src4[(size_t)grow * 120 + m];
            }
        }

        // ---- accumulate i2 taps intersecting rows [cs, cs+8) ----
#define ACC(ACCV, O2, C4) {                                                    \
            int jl = sjlo[O2];                                                 \
            int k0 = cs - jl;        if (k0 < 0) k0 = 0;                       \
            int k1 = cs + 8 - jl;    if (k1 > MT) k1 = MT;                     \
            int km = NI - jl;        if (k1 > km) k1 = km;                     \
            for (int k = k0; k < k1; ++k) {                                    \
                float w = sw1[(O2) * MT + k];                                  \
                const float4 v = *(const float4*)(&tc[(jl + k - cs) * PROW + (C4) * 4]); \
                ACCV.x += w * v.x; ACCV.y += w * v.y;                          \
                ACCV.z += w * v.z; ACCV.w += w * v.w;                          \
            }                                                                  \
        }
        ACC(acc0, o2_0, c4_0)
        ACC(acc1, o2_1, c4_1)
        if (idx2 < lim) ACC(acc2, o2_2, c4_2)
#undef ACC
        __syncthreads();                 // tc consumed + raw staged
    }

    float4* dst = (float4*)A2 + (size_t)slab * (NO * PROW4) + o2a * PROW4;
    dst[idx0] = acc0;
    dst[idx1] = acc1;
    if (idx2 < lim) dst[idx2] = acc2;
}

// Bijective XCD-chunked block swizzle (m204 form).
__device__ __forceinline__ int xcd_swz(int wg, int nwg) {
    int q = nwg >> 3, r = nwg & 7;
    int x = wg & 7, i = wg >> 3;
    return (x < r ? x * (q + 1) : r * (q + 1) + (x - r) * q) + i;
}

// ---------------------------------------------------------------------------
// P3: contract i1 -> o1.  out[b][o1][o2][o3][c] (unpadded 129 cols).
// (byte-identical to r9's passing k_p3)
// ---------------------------------------------------------------------------
__global__ __launch_bounds__(256) void k_p3(
        const float* __restrict__ A2, float* __restrict__ out) {
    int blk = xcd_swz(blockIdx.x, gridDim.x);
    size_t idx = (size_t)blk * 256 + threadIdx.x;
    if (idx >= P3_THREADS) return;
    int ii = (int)idx;
    int col4 = ii % PROW4;
    int o2   = (ii / PROW4) % NO;
    int o1   = (ii / (PROW4 * NO)) % NO;
    int b    = ii / (PROW4 * NO * NO);
    const char* base = (const char*)A2 +
        (((size_t)b * NI * NO + o2) * PROW + col4 * 4) * 4;
    const float4* wv = (const float4*)dT.w1[o1];
    const int4*   ov = (const int4*)dT.o0[o1];
    float4 w0 = wv[0], w1v = wv[1], w2 = wv[2], w3 = wv[3];
    int4   j0 = ov[0], j1 = ov[1], j2 = ov[2], j3 = ov[3];
    float4 a = {0.f, 0.f, 0.f, 0.f};
#define TAP4(J, W) { float4 v = *(const float4*)(base + (unsigned)(J)); \
                     a.x += (W) * v.x; a.y += (W) * v.y; a.z += (W) * v.z; a.w += (W) * v.w; }
    TAP4(j0.x, w0.x) TAP4(j0.y, w0.y) TAP4(j0.z, w0.z) TAP4(j0.w, w0.w)
    TAP4(j1.x, w1v.x) TAP4(j1.y, w1v.y) TAP4(j1.z, w1v.z) TAP4(j1.w, w1v.w)
    TAP4(j2.x, w2.x) TAP4(j2.y, w2.y) TAP4(j2.z, w2.z) TAP4(j2.w, w2.w)
    TAP4(j3.x, w3.x) TAP4(j3.y, w3.y) TAP4(j3.z, w3.z) TAP4(j3.w, w3.w)
#undef TAP4
    int tile = (b * NO + o1) * NO + o2;
    float* ob = out + (size_t)tile * (NO * NC) + col4 * 4;
    int col = col4 * 4;
    float av[4] = {a.x, a.y, a.z, a.w};
    #pragma unroll
    for (int e = 0; e < 4; ++e)
        if (col + e < NO * NC) ob[e] = av[e];
}

// ---------------------------------------------------------------------------
// FALLBACK (r1-structure, known-correct), setup-free. Used only if ws too small.
// ---------------------------------------------------------------------------
__global__ __launch_bounds__(256) void k_passA(
        const float* __restrict__ img, float* __restrict__ S) {
    __shared__ float rows[CH * NI * NC];
    __shared__ float T[CH * NO * NC];
    __shared__ float acc[NO * NO * NC];
    __shared__ float w2[NO * MT];
    __shared__ int   s2[NO];
    int t = threadIdx.x;
    int blk = blockIdx.x;
    const float* src = img + (size_t)blk * (NI * NI * NC);
    for (int k = t; k < NO * MT; k += 256) w2[k] = ((const float*)dT.w1)[k];
    for (int k = t; k < NO; k += 256) s2[k] = dT.jlo[k];
    for (int k = t; k < NO * NO * NC; k += 256) acc[k] = 0.f;
    __syncthreads();
    for (int chunk = 0; chunk < NI / CH; ++chunk) {
        const float4* csrc = (const float4*)(src + (size_t)chunk * CH * NI * NC);
        for (int k = t; k < CH * NI * NC / 4; k += 256)
            ((float4*)rows)[k] = csrc[k];
        __syncthreads();
        for (int task = t; task < CH * NO; task += 256) {
            int ch = task / NO, o3 = task % NO;
            int st = s2[o3];
            const float* rp = rows + ch * NI * NC;
            float a0 = 0.f, a1 = 0.f, a2 = 0.f;
            #pragma unroll
            for (int k = 0; k < MT; ++k) {
                int j = st + k; j = (j < NI) ? j : (NI - 1);
                float w = w2[o3 * MT + k];
                a0 += w * rp[j * 3 + 0];
                a1 += w * rp[j * 3 + 1];
                a2 += w * rp[j * 3 + 2];
            }
            T[task * NC + 0] = a0;
            T[task * NC + 1] = a1;
            T[task * NC + 2] = a2;
        }
        __syncthreads();
        int i2base = chunk * CH;
        for (int task = t; task < NO * NO; task += 256) {
            int o2 = task / NO, o3 = task % NO;
            int st = s2[o2];
            int k0 = i2base - st;        k0 = (k0 > 0) ? k0 : 0;
            int k1 = i2base + CH - st;   k1 = (k1 < MT) ? k1 : MT;
            if (k1 > k0) {
                float a0 = 0.f, a1 = 0.f, a2 = 0.f;
                for (int k = k0; k < k1; ++k) {
                    float w = w2[o2 * MT + k];
                    int ch = st + k - i2base;
                    a0 += w * T[(ch * NO + o3) * NC + 0];
                    a1 += w * T[(ch * NO + o3) * NC + 1];
                    a2 += w * T[(ch * NO + o3) * NC + 2];
                }
                acc[task * NC + 0] += a0;
                acc[task * NC + 1] += a1;
                acc[task * NC + 2] += a2;
            }
        }
        __syncthreads();
    }
    float* Sp = S + (size_t)blk * (NO * NO * NC);
    for (int k = t; k < NO * NO * NC; k += 256) Sp[k] = acc[k];
}

__global__ __launch_bounds__(256) void k_passB(
        const float* __restrict__ S, float* __restrict__ out) {
    int blk = blockIdx.x;
    int b = blk / NO, o1 = blk % NO;
    __shared__ float w1s[MT];
    __shared__ int s1v;
    if (threadIdx.x < MT) w1s[threadIdx.x] = dT.w1[o1][threadIdx.x];
    if (threadIdx.x == 0) s1v = dT.jlo[o1];
    __syncthreads();
    const float* Sb = S + (size_t)b * NI * (NO * NO * NC);
    float* ob = out + (size_t)blk * (NO * NO * NC);
    int st = s1v;
    for (int e = threadIdx.x; e < NO * NO * NC; e += 256) {
        float a = 0.f;
        #pragma unroll
        for (int k = 0; k < MT; ++k) {
            int i1 = st + k; i1 = (i1 < NI) ? i1 : (NI - 1);
            a += w1s[k] * Sb[(size_t)i1 * (NO * NO * NC) + e];
        }
        ob[e] = a;
    }
}

// ---------------------------------------------------------------------------
extern "C" void kernel_launch(void* const* d_in, const int* in_sizes, int n_in,
                              void* d_out, int out_size, void* d_ws, size_t ws_size,
                              hipStream_t stream) {
    (void)in_sizes; (void)n_in; (void)out_size;
    const float* img = (const float*)d_in[0];
    float* out = (float*)d_out;
    char* ws = (char*)d_ws;

    if (ws_size >= A2_BYTES) {
        float* A2 = (float*)ws;
        k_f2<<<NB * NI * 2, 256, 0, stream>>>(img, A2);
        int p3b = (int)((P3_THREADS + 255) / 256);
        k_p3<<<p3b, 256, 0, stream>>>(A2, out);
    } else {
        float* S = (float*)ws;                       // 14.2 MB
        k_passA<<<NB * NI, 256, 0, stream>>>(img, S);
        k_passB<<<NB * NO, 256, 0, stream>>>(S, out);
    }
}

// Round 12
// 80.856 us; speedup vs baseline: 1.2054x; 1.2054x over previous
//
#include <hip/hip_runtime.h>
#include <hip/hip_fp16.h>

// Problem constants
#define NB 4      // batch
#define NI 160    // input spatial size (all 3 dims)
#define NO 43     // output spatial size: ceil(160/4)+3
#define NC 3      // channels
#define KS 7      // gaussian kernel size per axis
#define KPAD 3    // (KS-1)/2
#define MT 16     // stored taps per banded row (true max = 14)
#define CH 8      // rows per chunk (fallback)

#define ROWF (NI * NC)            // 480 floats per input row
#define PROW 132                  // padded (o3,c) row: 129 -> 132 elems
#define PROW4 (PROW / 4)          // 33 groups of 4
#define LROW 484                  // LDS row stride (484 % 32 == 4)
#define SLICE (NO * NO * NC)

#define A1H_BYTES ((size_t)NB * NI * NI * PROW * 2)      // 27,033,600 (fp16)
#define A2_BYTES  ((size_t)NB * NI * NO * PROW * 4)      // 14,530,560 (fp32)
#define P2_THREADS ((size_t)NB * NI * NO * PROW4)        // 908,160
#define P3_THREADS ((size_t)NB * NO * NO * PROW4)        // 244,068

// ===========================================================================
// Compile-time weight tables (validated r8/r9/r11-pre, absmax <= 9.8e-4).
// ===========================================================================
struct __align__(16) Tables {
    float wa3[NO][20];   // aligned 20-float composite windows (i3 contraction)
    float w1[NO][MT];    // banded 16-tap composite weights (shared by axes)
    int   o1h[NO][MT];   // clamped byte offsets, stride PROW*2 = 264 (p2, fp16 A1)
    int   o0[NO][MT];    // clamped byte offsets, stride NO*PROW*4 = 22704 (p3)
    int   j3[NO];        // aligned window starts (multiples of 4)
    int   jlo[NO];       // band starts
};

constexpr double ctaylor(double r) {            // exp(r), r in [0, 1/16]
    double s = 1.0, term = 1.0;
    for (int n = 1; n <= 13; ++n) { term *= r / (double)n; s += term; }
    return s;
}
constexpr double cexp_neg(double x) {           // exp(x), x <= 0, |x| < 40
    double y = -x;
    int k = (int)(y * 16.0);
    double r = y - (double)k / 16.0;
    double e16 = ctaylor(1.0 / 16.0);
    double p = 1.0;
    for (int i = 0; i < k; ++i) p *= e16;
    return 1.0 / (p * ctaylor(r));
}
constexpr int cceil(double x)  { int c = (int)x; return ((double)c < x) ? c + 1 : c; }
constexpr int cfloor(double x) { int f = (int)x; return ((double)f > x) ? f - 1 : f; }
constexpr double cabsd(double x) { return x < 0 ? -x : x; }

constexpr double comp_w(int j, double sf, int ilo, int ihi, const double* g) {
    if (j >= NI || j < 0) return 0.0;           // taps at j>=NI are exactly 0
    double cw = 0.0;
    for (int t = 0; t < KS; ++t) {
        int i = j + KPAD - t;
        if (i >= ilo && i <= ihi) {
            double w = 1.0 - cabsd(sf - (double)i) * (43.0 / 160.0);
            if (w > 0.0) cw += g[t] * w;
        }
    }
    return cw;
}

constexpr Tables make_tables() {
    Tables T{};
    double g[KS] = {};
    double gs = 0.0;
    const double sig = 0.44 * 4.0;
    for (int i = 0; i < KS; ++i) {
        double d = (double)i - 3.0;
        g[i] = cexp_neg(-(d * d) / (2.0 * sig * sig));
        gs += g[i];
    }
    for (int i = 0; i < KS; ++i) g[i] /= gs;

    const double inv_scale = 160.0 / 43.0;
    for (int o = 0; o < NO; ++o) {
        double sf = ((double)o + 0.5) * inv_scale - 0.5;
        int ilo = cceil(sf - inv_scale);  if (ilo < 0) ilo = 0;
        int ihi = cfloor(sf + inv_scale); if (ihi > NI - 1) ihi = NI - 1;
        double wsum = 0.0;
        for (int i = ilo; i <= ihi; ++i) {
            double w = 1.0 - cabsd(sf - (double)i) * (43.0 / 160.0);
            if (w > 0.0) wsum += w;
        }
        int jlo = ilo - KPAD; if (jlo < 0) jlo = 0;
        int j0 = jlo & ~3;
        T.j3[o] = j0;
        T.jlo[o] = jlo;
        for (int m = 0; m < 20; ++m)
            T.wa3[o][m] = (float)(comp_w(j0 + m, sf, ilo, ihi, g) / wsum);
        for (int k = 0; k < MT; ++k) {
            int j = jlo + k;
            T.w1[o][k] = (float)(comp_w(j, sf, ilo, ihi, g) / wsum);
            int jc = (j < NI) ? j : (NI - 1);       // pad taps have w=0
            T.o1h[o][k] = jc * (PROW * 2);          // fp16 row stride 264 B
            T.o0[o][k]  = jc * (NO * PROW * 4);
        }
    }
    return T;
}

__constant__ Tables dT = make_tables();

struct __align__(8) h4 { __half2 lo, hi; };

// ---------------------------------------------------------------------------
// P1: contract i3 -> o3.  A1h[b][i1][i2][o3*3+c] in fp16 (rows padded to 132).
// r11 post-timing fix: results go to an LDS fp16 tile first; the global
// flush is 132 cooperative uint4 stores (16B, aligned) — ZERO sub-dword
// global stores (different threads never touch the same dword).
// ---------------------------------------------------------------------------
__global__ __launch_bounds__(256, 4) void k_p1(
        const float* __restrict__ img, __half* __restrict__ A1h) {
    __shared__ __align__(16) float rows[8 * LROW + 64];   // 3936 f
    __shared__ __align__(16) float swa[NO * 20];          // 860 f
    __shared__ __align__(16) __half hs[8 * PROW];         // 1056 halves, 2112 B
    __shared__ int sj0[NO];
    int t = threadIdx.x;
    int blk = blockIdx.x;                                  // (b*160+i1)*20 + chunk

    const float4* src = (const float4*)(img + (size_t)blk * (8 * ROWF));
    for (int gidx = t; gidx < 8 * ROWF / 4; gidx += 256) {
        int row = gidx / (ROWF / 4), m = gidx % (ROWF / 4);
        *(float4*)(rows + row * LROW + 4 * m) = src[gidx];
    }
    if (t < 32) rows[(t >> 2) * LROW + ROWF + (t & 3)] = 0.f;
    if (t < 64) rows[8 * LROW + t] = 0.f;
    for (int k = t; k < NO * 20; k += 256) swa[k] = ((const float*)dT.wa3)[k];
    if (t < NO) sj0[t] = dT.j3[t];
    __syncthreads();

    for (int task = t; task < NO * 8; task += 256) {
        int o3 = task >> 3, row = task & 7;
        int j0 = sj0[o3];
        const float4* dp = (const float4*)(rows + row * LROW + 3 * j0);
        const float4* wp = (const float4*)(swa + o3 * 20);
        float d[60], wv[20];
        #pragma unroll
        for (int m = 0; m < 15; ++m) {
            float4 v = dp[m];
            d[4 * m + 0] = v.x; d[4 * m + 1] = v.y;
            d[4 * m + 2] = v.z; d[4 * m + 3] = v.w;
        }
        #pragma unroll
        for (int m = 0; m < 5; ++m) {
            float4 v = wp[m];
            wv[4 * m + 0] = v.x; wv[4 * m + 1] = v.y;
            wv[4 * m + 2] = v.z; wv[4 * m + 3] = v.w;
        }
        float a0 = 0.f, a1 = 0.f, a2 = 0.f;
        #pragma unroll
        for (int jj = 0; jj < 20; ++jj) {
            float w = wv[jj];
            a0 += w * d[3 * jj + 0];
            a1 += w * d[3 * jj + 1];
            a2 += w * d[3 * jj + 2];
        }
        __half* op = hs + row * PROW + o3 * 3;      // LDS: byte-granular safe
        op[0] = __float2half(a0); op[1] = __float2half(a1); op[2] = __float2half(a2);
    }
    if (t < 8) {                                    // pad cols 129..131 (LDS)
        __half* op = hs + t * PROW + NO * NC;
        op[0] = __half(0.f); op[1] = __half(0.f); op[2] = __half(0.f);
    }
    __syncthreads();

    // dword-granular global flush: 132 x uint4 (16 B), dst 16B-aligned
    uint4* d4 = (uint4*)(A1h + (size_t)blk * (8 * PROW));
    const uint4* s4 = (const uint4*)hs;
    for (int k = t; k < 132; k += 256) d4[k] = s4[k];
}

// Bijective XCD-chunked block swizzle (m204 form).
__device__ __forceinline__ int xcd_swz(int wg, int nwg) {
    int q = nwg >> 3, r = nwg & 7;
    int x = wg & 7, i = wg >> 3;
    return (x < r ? x * (q + 1) : r * (q + 1) + (x - r) * q) + i;
}

// ---------------------------------------------------------------------------
// P2: contract i2 -> o2.  A2[b][i1][o2][132] fp32. Thread per 4 cols;
// taps are 8B half4 loads from fp16 A1 (L2/L3-hot), converted in-register.
// ---------------------------------------------------------------------------
__global__ __launch_bounds__(256) void k_p2(
        const __half* __restrict__ A1h, float* __restrict__ A2) {
    int blk = xcd_swz(blockIdx.x, gridDim.x);
    size_t idx = (size_t)blk * 256 + threadIdx.x;
    if (idx >= P2_THREADS) return;
    int ii = (int)idx;
    int col4 = ii % PROW4;
    int o2   = (ii / PROW4) % NO;
    int slab = ii / (PROW4 * NO);           // b*160 + i1
    const char* base = (const char*)A1h + ((size_t)slab * NI * PROW + col4 * 4) * 2;
    const float4* wv = (const float4*)dT.w1[o2];
    const int4*   ov = (const int4*)dT.o1h[o2];
    float4 w0 = wv[0], w1v = wv[1], w2 = wv[2], w3 = wv[3];
    int4   j0 = ov[0], j1 = ov[1], j2 = ov[2], j3 = ov[3];
    float4 a = {0.f, 0.f, 0.f, 0.f};
#define TAP4H(J, W) { h4 v = *(const h4*)(base + (unsigned)(J));               \
                      float2 f0 = __half22float2(v.lo);                        \
                      float2 f1 = __half22float2(v.hi);                        \
                      a.x += (W) * f0.x; a.y += (W) * f0.y;                    \
                      a.z += (W) * f1.x; a.w += (W) * f1.y; }
    TAP4H(j0.x, w0.x) TAP4H(j0.y, w0.y) TAP4H(j0.z, w0.z) TAP4H(j0.w, w0.w)
    TAP4H(j1.x, w1v.x) TAP4H(j1.y, w1v.y) TAP4H(j1.z, w1v.z) TAP4H(j1.w, w1v.w)
    TAP4H(j2.x, w2.x) TAP4H(j2.y, w2.y) TAP4H(j2.z, w2.z) TAP4H(j2.w, w2.w)
    TAP4H(j3.x, w3.x) TAP4H(j3.y, w3.y) TAP4H(j3.z, w3.z) TAP4H(j3.w, w3.w)
#undef TAP4H
    ((float4*)A2)[idx] = a;
}

// ---------------------------------------------------------------------------
// P3: contract i1 -> o1.  out[b][o1][o2][o3][c] (unpadded 129 cols).
// (byte-identical to r9's passing k_p3)
// ---------------------------------------------------------------------------
__global__ __launch_bounds__(256) void k_p3(
        const float* __restrict__ A2, float* __restrict__ out) {
    int blk = xcd_swz(blockIdx.x, gridDim.x);
    size_t idx = (size_t)blk * 256 + threadIdx.x;
    if (idx >= P3_THREADS) return;
    int ii = (int)idx;
    int col4 = ii % PROW4;
    int o2   = (ii / PROW4) % NO;
    int o1   = (ii / (PROW4 * NO)) % NO;
    int b    = ii / (PROW4 * NO * NO);
    const char* base = (const char*)A2 +
        (((size_t)b * NI * NO + o2) * PROW + col4 * 4) * 4;
    const float4* wv = (const float4*)dT.w1[o1];
    const int4*   ov = (const int4*)dT.o0[o1];
    float4 w0 = wv[0], w1v = wv[1], w2 = wv[2], w3 = wv[3];
    int4   j0 = ov[0], j1 = ov[1], j2 = ov[2], j3 = ov[3];
    float4 a = {0.f, 0.f, 0.f, 0.f};
#define TAP4(J, W) { float4 v = *(const float4*)(base + (unsigned)(J)); \
                     a.x += (W) * v.x; a.y += (W) * v.y; a.z += (W) * v.z; a.w += (W) * v.w; }
    TAP4(j0.x, w0.x) TAP4(j0.y, w0.y) TAP4(j0.z, w0.z) TAP4(j0.w, w0.w)
    TAP4(j1.x, w1v.x) TAP4(j1.y, w1v.y) TAP4(j1.z, w1v.z) TAP4(j1.w, w1v.w)
    TAP4(j2.x, w2.x) TAP4(j2.y, w2.y) TAP4(j2.z, w2.z) TAP4(j2.w, w2.w)
    TAP4(j3.x, w3.x) TAP4(j3.y, w3.y) TAP4(j3.z, w3.z) TAP4(j3.w, w3.w)
#undef TAP4
    int tile = (b * NO + o1) * NO + o2;
    float* ob = out + (size_t)tile * (NO * NC) + col4 * 4;
    int col = col4 * 4;
    float av[4] = {a.x, a.y, a.z, a.w};
    #pragma unroll
    for (int e = 0; e < 4; ++e)
        if (col + e < NO * NC) ob[e] = av[e];
}

// ---------------------------------------------------------------------------
// FALLBACK (r1-structure, known-correct), fp32, setup-free.
// ---------------------------------------------------------------------------
__global__ __launch_bounds__(256) void k_passA(
        const float* __restrict__ img, float* __restrict__ S) {
    __shared__ float rows[CH * NI * NC];
    __shared__ float T[CH * NO * NC];
    __shared__ float acc[NO * NO * NC];
    __shared__ float w2[NO * MT];
    __shared__ int   s2[NO];
    int t = threadIdx.x;
    int blk = blockIdx.x;
    const float* src = img + (size_t)blk * (NI * NI * NC);
    for (int k = t; k < NO * MT; k += 256) w2[k] = ((const float*)dT.w1)[k];
    for (int k = t; k < NO; k += 256) s2[k] = dT.jlo[k];
    for (int k = t; k < NO * NO * NC; k += 256) acc[k] = 0.f;
    __syncthreads();
    for (int chunk = 0; chunk < NI / CH; ++chunk) {
        const float4* csrc = (const float4*)(src + (size_t)chunk * CH * NI * NC);
        for (int k = t; k < CH * NI * NC / 4; k += 256)
            ((float4*)rows)[k] = csrc[k];
        __syncthreads();
        for (int task = t; task < CH * NO; task += 256) {
            int ch = task / NO, o3 = task % NO;
            int st = s2[o3];
            const float* rp = rows + ch * NI * NC;
            float a0 = 0.f, a1 = 0.f, a2 = 0.f;
            #pragma unroll
            for (int k = 0; k < MT; ++k) {
                int j = st + k; j = (j < NI) ? j : (NI - 1);
                float w = w2[o3 * MT + k];
                a0 += w * rp[j * 3 + 0];
                a1 += w * rp[j * 3 + 1];
                a2 += w * rp[j * 3 + 2];
            }
            T[task * NC + 0] = a0;
            T[task * NC + 1] = a1;
            T[task * NC + 2] = a2;
        }
        __syncthreads();
        int i2base = chunk * CH;
        for (int task = t; task < NO * NO; task += 256) {
            int o2 = task / NO, o3 = task % NO;
            int st = s2[o2];
            int k0 = i2base - st;        k0 = (k0 > 0) ? k0 : 0;
            int k1 = i2base + CH - st;   k1 = (k1 < MT) ? k1 : MT;
            if (k1 > k0) {
                float a0 = 0.f, a1 = 0.f, a2 = 0.f;
                for (int k = k0; k < k1; ++k) {
                    float w = w2[o2 * MT + k];
                    int ch = st + k - i2base;
                    a0 += w * T[(ch * NO + o3) * NC + 0];
                    a1 += w * T[(ch * NO + o3) * NC + 1];
                    a2 += w * T[(ch * NO + o3) * NC + 2];
                }
                acc[task * NC + 0] += a0;
                acc[task * NC + 1] += a1;
                acc[task * NC + 2] += a2;
            }
        }
        __syncthreads();
    }
    float* Sp = S + (size_t)blk * (NO * NO * NC);
    for (int k = t; k < NO * NO * NC; k += 256) Sp[k] = acc[k];
}

__global__ __launch_bounds__(256) void k_passB(
        const float* __restrict__ S, float* __restrict__ out) {
    int blk = blockIdx.x;
    int b = blk / NO, o1 = blk % NO;
    __shared__ float w1s[MT];
    __shared__ int s1v;
    if (threadIdx.x < MT) w1s[threadIdx.x] = dT.w1[o1][threadIdx.x];
    if (threadIdx.x == 0) s1v = dT.jlo[o1];
    __syncthreads();
    const float* Sb = S + (size_t)b * NI * (NO * NO * NC);
    float* ob = out + (size_t)blk * (NO * NO * NC);
    int st = s1v;
    for (int e = threadIdx.x; e < NO * NO * NC; e += 256) {
        float a = 0.f;
        #pragma unroll
        for (int k = 0; k < MT; ++k) {
            int i1 = st + k; i1 = (i1 < NI) ? i1 : (NI - 1);
            a += w1s[k] * Sb[(size_t)i1 * (NO * NO * NC) + e];
        }
        ob[e] = a;
    }
}

// ---------------------------------------------------------------------------
extern "C" void kernel_launch(void* const* d_in, const int* in_sizes, int n_in,
                              void* d_out, int out_size, void* d_ws, size_t ws_size,
                              hipStream_t stream) {
    (void)in_sizes; (void)n_in; (void)out_size;
    const float* img = (const float*)d_in[0];
    float* out = (float*)d_out;
    char* ws = (char*)d_ws;

    if (ws_size >= A1H_BYTES + A2_BYTES) {
        __half* A1h = (__half*)ws;
        float*  A2  = (float*)(ws + A1H_BYTES);
        k_p1<<<NB * NI * (NI / 8), 256, 0, stream>>>(img, A1h);
        int p2b = (int)((P2_THREADS + 255) / 256);
        k_p2<<<p2b, 256, 0, stream>>>(A1h, A2);
        int p3b = (int)((P3_THREADS + 255) / 256);
        k_p3<<<p3b, 256, 0, stream>>>(A2, out);
    } else {
        float* S = (float*)ws;                       // 14.2 MB
        k_passA<<<NB * NI, 256, 0, stream>>>(img, S);
        k_passB<<<NB * NO, 256, 0, stream>>>(S, out);
    }
}

// Round 13
// 71.747 us; speedup vs baseline: 1.3584x; 1.1270x over previous
//
#include <hip/hip_runtime.h>
#include <hip/hip_fp16.h>

// Problem constants
#define NB 4      // batch
#define NI 160    // input spatial size (all 3 dims)
#define NO 43     // output spatial size: ceil(160/4)+3
#define NC 3      // channels
#define KS 7      // gaussian kernel size per axis
#define KPAD 3    // (KS-1)/2
#define MT 16     // stored taps per banded row (true max = 14)
#define CH 8      // rows per chunk (fallback)
#define CH1 4     // rows per chunk in k_p1 (small => 8 blocks/CU co-resident)

#define ROWF (NI * NC)            // 480 floats per input row
#define PROW 132                  // padded (o3,c) row: 129 -> 132 elems
#define PROW4 (PROW / 4)          // 33 groups of 4
#define LROW 484                  // LDS row stride (484 % 32 == 4)
#define SLICE (NO * NO * NC)

#define A1H_BYTES ((size_t)NB * NI * NI * PROW * 2)      // 27,033,600 (fp16)
#define A2_BYTES  ((size_t)NB * NI * NO * PROW * 4)      // 14,530,560 (fp32)
#define P2_THREADS ((size_t)NB * NI * NO * PROW4)        // 908,160
#define P3_THREADS ((size_t)NB * NO * NO * PROW4)        // 244,068

// ===========================================================================
// Compile-time weight tables (validated r8/r9/r12, absmax <= 9.8e-4).
// ===========================================================================
struct __align__(16) Tables {
    float wa3[NO][20];   // aligned 20-float composite windows (i3 contraction)
    float w1[NO][MT];    // banded 16-tap composite weights (shared by axes)
    int   o1h[NO][MT];   // clamped byte offsets, stride PROW*2 = 264 (p2, fp16 A1)
    int   o0[NO][MT];    // clamped byte offsets, stride NO*PROW*4 = 22704 (p3)
    int   j3[NO];        // aligned window starts (multiples of 4)
    int   jlo[NO];       // band starts
};

constexpr double ctaylor(double r) {            // exp(r), r in [0, 1/16]
    double s = 1.0, term = 1.0;
    for (int n = 1; n <= 13; ++n) { term *= r / (double)n; s += term; }
    return s;
}
constexpr double cexp_neg(double x) {           // exp(x), x <= 0, |x| < 40
    double y = -x;
    int k = (int)(y * 16.0);
    double r = y - (double)k / 16.0;
    double e16 = ctaylor(1.0 / 16.0);
    double p = 1.0;
    for (int i = 0; i < k; ++i) p *= e16;
    return 1.0 / (p * ctaylor(r));
}
constexpr int cceil(double x)  { int c = (int)x; return ((double)c < x) ? c + 1 : c; }
constexpr int cfloor(double x) { int f = (int)x; return ((double)f > x) ? f - 1 : f; }
constexpr double cabsd(double x) { return x < 0 ? -x : x; }

constexpr double comp_w(int j, double sf, int ilo, int ihi, const double* g) {
    if (j >= NI || j < 0) return 0.0;           // taps at j>=NI are exactly 0
    double cw = 0.0;
    for (int t = 0; t < KS; ++t) {
        int i = j + KPAD - t;
        if (i >= ilo && i <= ihi) {
            double w = 1.0 - cabsd(sf - (double)i) * (43.0 / 160.0);
            if (w > 0.0) cw += g[t] * w;
        }
    }
    return cw;
}

constexpr Tables make_tables() {
    Tables T{};
    double g[KS] = {};
    double gs = 0.0;
    const double sig = 0.44 * 4.0;
    for (int i = 0; i < KS; ++i) {
        double d = (double)i - 3.0;
        g[i] = cexp_neg(-(d * d) / (2.0 * sig * sig));
        gs += g[i];
    }
    for (int i = 0; i < KS; ++i) g[i] /= gs;

    const double inv_scale = 160.0 / 43.0;
    for (int o = 0; o < NO; ++o) {
        double sf = ((double)o + 0.5) * inv_scale - 0.5;
        int ilo = cceil(sf - inv_scale);  if (ilo < 0) ilo = 0;
        int ihi = cfloor(sf + inv_scale); if (ihi > NI - 1) ihi = NI - 1;
        double wsum = 0.0;
        for (int i = ilo; i <= ihi; ++i) {
            double w = 1.0 - cabsd(sf - (double)i) * (43.0 / 160.0);
            if (w > 0.0) wsum += w;
        }
        int jlo = ilo - KPAD; if (jlo < 0) jlo = 0;
        int j0 = jlo & ~3;
        T.j3[o] = j0;
        T.jlo[o] = jlo;
        for (int m = 0; m < 20; ++m)
            T.wa3[o][m] = (float)(comp_w(j0 + m, sf, ilo, ihi, g) / wsum);
        for (int k = 0; k < MT; ++k) {
            int j = jlo + k;
            T.w1[o][k] = (float)(comp_w(j, sf, ilo, ihi, g) / wsum);
            int jc = (j < NI) ? j : (NI - 1);       // pad taps have w=0
            T.o1h[o][k] = jc * (PROW * 2);          // fp16 row stride 264 B
            T.o0[o][k]  = jc * (NO * PROW * 4);
        }
    }
    return T;
}

__constant__ Tables dT = make_tables();

struct __align__(8) h4 { __half2 lo, hi; };

// ---------------------------------------------------------------------------
// P1 (r13): contract i3 -> o3 into fp16 A1h. 4-row chunks, 25600 blocks,
// ~9 KB LDS -> 8 blocks/CU co-resident (stall interleaving); weights
// preloaded to REGISTERS from __constant__ dT before the barrier (off the
// LDS pipe, latency hidden under staging). One task per thread (172 <= 256).
// Global stores stay dword-granular via the hs LDS tile (r12 lesson).
// ---------------------------------------------------------------------------
__global__ __launch_bounds__(256, 4) void k_p1(
        const float* __restrict__ img, __half* __restrict__ A1h) {
    __shared__ __align__(16) float rows[CH1 * LROW + 64];  // 2000 f = 8 KB
    __shared__ __align__(16) __half hs[CH1 * PROW];        // 528 halves
    int t = threadIdx.x;
    int blk = blockIdx.x;                  // (b*160+i1)*40 + chunk

    const int o3 = t >> 2, row = t & 3;    // valid when t < 172
    const bool has_task = (t < NO * CH1);

    // weight preload (constant mem -> regs; independent of LDS staging)
    float4 wq0, wq1, wq2, wq3, wq4;
    int j0 = 0;
    if (has_task) {
        j0 = dT.j3[o3];
        const float4* wp = (const float4*)dT.wa3[o3];
        wq0 = wp[0]; wq1 = wp[1]; wq2 = wp[2]; wq3 = wp[3]; wq4 = wp[4];
    }

    // stage 4 rows (480 float4, coalesced)
    const float4* src = (const float4*)(img + (size_t)blk * (CH1 * ROWF));
    for (int g = t; g < CH1 * ROWF / 4; g += 256) {
        int r = g / 120, m = g % 120;
        *(float4*)(rows + r * LROW + 4 * m) = src[g];
    }
    if (t < 16) rows[(t >> 2) * LROW + ROWF + (t & 3)] = 0.f;   // row pads
    if (t >= 16 && t < 80) rows[CH1 * LROW + (t - 16)] = 0.f;   // tail slack
    __syncthreads();

    if (has_task) {
        const float4* dp = (const float4*)(rows + row * LROW + 3 * j0);
        float d[60], wv[20];
        #pragma unroll
        for (int m = 0; m < 15; ++m) {
            float4 v = dp[m];
            d[4 * m + 0] = v.x; d[4 * m + 1] = v.y;
            d[4 * m + 2] = v.z; d[4 * m + 3] = v.w;
        }
        wv[0]=wq0.x; wv[1]=wq0.y; wv[2]=wq0.z; wv[3]=wq0.w;
        wv[4]=wq1.x; wv[5]=wq1.y; wv[6]=wq1.z; wv[7]=wq1.w;
        wv[8]=wq2.x; wv[9]=wq2.y; wv[10]=wq2.z; wv[11]=wq2.w;
        wv[12]=wq3.x; wv[13]=wq3.y; wv[14]=wq3.z; wv[15]=wq3.w;
        wv[16]=wq4.x; wv[17]=wq4.y; wv[18]=wq4.z; wv[19]=wq4.w;
        float a0 = 0.f, a1 = 0.f, a2 = 0.f;
        #pragma unroll
        for (int jj = 0; jj < 20; ++jj) {
            float w = wv[jj];
            a0 += w * d[3 * jj + 0];
            a1 += w * d[3 * jj + 1];
            a2 += w * d[3 * jj + 2];
        }
        __half* op = hs + row * PROW + o3 * 3;      // LDS: byte-granular safe
        op[0] = __float2half(a0); op[1] = __float2half(a1); op[2] = __float2half(a2);
    }
    if (t >= 252) {                                 // pad cols 129..131 per row
        __half* op = hs + (t - 252) * PROW + NO * NC;
        op[0] = __half(0.f); op[1] = __half(0.f); op[2] = __half(0.f);
    }
    __syncthreads();

    // dword-granular global flush: 66 x uint4 (16 B), dst 16B-aligned
    uint4* d4 = (uint4*)(A1h + (size_t)blk * (CH1 * PROW));
    const uint4* s4 = (const uint4*)hs;
    if (t < 66) d4[t] = s4[t];
}

// Bijective XCD-chunked block swizzle (m204 form).
__device__ __forceinline__ int xcd_swz(int wg, int nwg) {
    int q = nwg >> 3, r = nwg & 7;
    int x = wg & 7, i = wg >> 3;
    return (x < r ? x * (q + 1) : r * (q + 1) + (x - r) * q) + i;
}

// ---------------------------------------------------------------------------
// P2: contract i2 -> o2.  A2[b][i1][o2][132] fp32. Thread per 4 cols;
// taps are 8B half4 loads from fp16 A1 (L2/L3-hot), converted in-register.
// (byte-identical to r12's passing k_p2)
// ---------------------------------------------------------------------------
__global__ __launch_bounds__(256) void k_p2(
        const __half* __restrict__ A1h, float* __restrict__ A2) {
    int blk = xcd_swz(blockIdx.x, gridDim.x);
    size_t idx = (size_t)blk * 256 + threadIdx.x;
    if (idx >= P2_THREADS) return;
    int ii = (int)idx;
    int col4 = ii % PROW4;
    int o2   = (ii / PROW4) % NO;
    int slab = ii / (PROW4 * NO);           // b*160 + i1
    const char* base = (const char*)A1h + ((size_t)slab * NI * PROW + col4 * 4) * 2;
    const float4* wv = (const float4*)dT.w1[o2];
    const int4*   ov = (const int4*)dT.o1h[o2];
    float4 w0 = wv[0], w1v = wv[1], w2 = wv[2], w3 = wv[3];
    int4   j0 = ov[0], j1 = ov[1], j2 = ov[2], j3 = ov[3];
    float4 a = {0.f, 0.f, 0.f, 0.f};
#define TAP4H(J, W) { h4 v = *(const h4*)(base + (unsigned)(J));               \
                      float2 f0 = __half22float2(v.lo);                        \
                      float2 f1 = __half22float2(v.hi);                        \
                      a.x += (W) * f0.x; a.y += (W) * f0.y;                    \
                      a.z += (W) * f1.x; a.w += (W) * f1.y; }
    TAP4H(j0.x, w0.x) TAP4H(j0.y, w0.y) TAP4H(j0.z, w0.z) TAP4H(j0.w, w0.w)
    TAP4H(j1.x, w1v.x) TAP4H(j1.y, w1v.y) TAP4H(j1.z, w1v.z) TAP4H(j1.w, w1v.w)
    TAP4H(j2.x, w2.x) TAP4H(j2.y, w2.y) TAP4H(j2.z, w2.z) TAP4H(j2.w, w2.w)
    TAP4H(j3.x, w3.x) TAP4H(j3.y, w3.y) TAP4H(j3.z, w3.z) TAP4H(j3.w, w3.w)
#undef TAP4H
    ((float4*)A2)[idx] = a;
}

// ---------------------------------------------------------------------------
// P3: contract i1 -> o1.  out[b][o1][o2][o3][c] (unpadded 129 cols).
// (byte-identical to r12's passing k_p3)
// ---------------------------------------------------------------------------
__global__ __launch_bounds__(256) void k_p3(
        const float* __restrict__ A2, float* __restrict__ out) {
    int blk = xcd_swz(blockIdx.x, gridDim.x);
    size_t idx = (size_t)blk * 256 + threadIdx.x;
    if (idx >= P3_THREADS) return;
    int ii = (int)idx;
    int col4 = ii % PROW4;
    int o2   = (ii / PROW4) % NO;
    int o1   = (ii / (PROW4 * NO)) % NO;
    int b    = ii / (PROW4 * NO * NO);
    const char* base = (const char*)A2 +
        (((size_t)b * NI * NO + o2) * PROW + col4 * 4) * 4;
    const float4* wv = (const float4*)dT.w1[o1];
    const int4*   ov = (const int4*)dT.o0[o1];
    float4 w0 = wv[0], w1v = wv[1], w2 = wv[2], w3 = wv[3];
    int4   j0 = ov[0], j1 = ov[1], j2 = ov[2], j3 = ov[3];
    float4 a = {0.f, 0.f, 0.f, 0.f};
#define TAP4(J, W) { float4 v = *(const float4*)(base + (unsigned)(J)); \
                     a.x += (W) * v.x; a.y += (W) * v.y; a.z += (W) * v.z; a.w += (W) * v.w; }
    TAP4(j0.x, w0.x) TAP4(j0.y, w0.y) TAP4(j0.z, w0.z) TAP4(j0.w, w0.w)
    TAP4(j1.x, w1v.x) TAP4(j1.y, w1v.y) TAP4(j1.z, w1v.z) TAP4(j1.w, w1v.w)
    TAP4(j2.x, w2.x) TAP4(j2.y, w2.y) TAP4(j2.z, w2.z) TAP4(j2.w, w2.w)
    TAP4(j3.x, w3.x) TAP4(j3.y, w3.y) TAP4(j3.z, w3.z) TAP4(j3.w, w3.w)
#undef TAP4
    int tile = (b * NO + o1) * NO + o2;
    float* ob = out + (size_t)tile * (NO * NC) + col4 * 4;
    int col = col4 * 4;
    float av[4] = {a.x, a.y, a.z, a.w};
    #pragma unroll
    for (int e = 0; e < 4; ++e)
        if (col + e < NO * NC) ob[e] = av[e];
}

// ---------------------------------------------------------------------------
// FALLBACK (r1-structure, known-correct), fp32, setup-free.
// ---------------------------------------------------------------------------
__global__ __launch_bounds__(256) void k_passA(
        const float* __restrict__ img, float* __restrict__ S) {
    __shared__ float rows[CH * NI * NC];
    __shared__ float T[CH * NO * NC];
    __shared__ float acc[NO * NO * NC];
    __shared__ float w2[NO * MT];
    __shared__ int   s2[NO];
    int t = threadIdx.x;
    int blk = blockIdx.x;
    const float* src = img + (size_t)blk * (NI * NI * NC);
    for (int k = t; k < NO * MT; k += 256) w2[k] = ((const float*)dT.w1)[k];
    for (int k = t; k < NO; k += 256) s2[k] = dT.jlo[k];
    for (int k = t; k < NO * NO * NC; k += 256) acc[k] = 0.f;
    __syncthreads();
    for (int chunk = 0; chunk < NI / CH; ++chunk) {
        const float4* csrc = (const float4*)(src + (size_t)chunk * CH * NI * NC);
        for (int k = t; k < CH * NI * NC / 4; k += 256)
            ((float4*)rows)[k] = csrc[k];
        __syncthreads();
        for (int task = t; task < CH * NO; task += 256) {
            int ch = task / NO, o3 = task % NO;
            int st = s2[o3];
            const float* rp = rows + ch * NI * NC;
            float a0 = 0.f, a1 = 0.f, a2 = 0.f;
            #pragma unroll
            for (int k = 0; k < MT; ++k) {
                int j = st + k; j = (j < NI) ? j : (NI - 1);
                float w = w2[o3 * MT + k];
                a0 += w * rp[j * 3 + 0];
                a1 += w * rp[j * 3 + 1];
                a2 += w * rp[j * 3 + 2];
            }
            T[task * NC + 0] = a0;
            T[task * NC + 1] = a1;
            T[task * NC + 2] = a2;
        }
        __syncthreads();
        int i2base = chunk * CH;
        for (int task = t; task < NO * NO; task += 256) {
            int o2 = task / NO, o3 = task % NO;
            int st = s2[o2];
            int k0 = i2base - st;        k0 = (k0 > 0) ? k0 : 0;
            int k1 = i2base + CH - st;   k1 = (k1 < MT) ? k1 : MT;
            if (k1 > k0) {
                float a0 = 0.f, a1 = 0.f, a2 = 0.f;
                for (int k = k0; k < k1; ++k) {
                    float w = w2[o2 * MT + k];
                    int ch = st + k - i2base;
                    a0 += w * T[(ch * NO + o3) * NC + 0];
                    a1 += w * T[(ch * NO + o3) * NC + 1];
                    a2 += w * T[(ch * NO + o3) * NC + 2];
                }
                acc[task * NC + 0] += a0;
                acc[task * NC + 1] += a1;
                acc[task * NC + 2] += a2;
            }
        }
        __syncthreads();
    }
    float* Sp = S + (size_t)blk * (NO * NO * NC);
    for (int k = t; k < NO * NO * NC; k += 256) Sp[k] = acc[k];
}

__global__ __launch_bounds__(256) void k_passB(
        const float* __restrict__ S, float* __restrict__ out) {
    int blk = blockIdx.x;
    int b = blk / NO, o1 = blk % NO;
    __shared__ float w1s[MT];
    __shared__ int s1v;
    if (threadIdx.x < MT) w1s[threadIdx.x] = dT.w1[o1][threadIdx.x];
    if (threadIdx.x == 0) s1v = dT.jlo[o1];
    __syncthreads();
    const float* Sb = S + (size_t)b * NI * (NO * NO * NC);
    float* ob = out + (size_t)blk * (NO * NO * NC);
    int st = s1v;
    for (int e = threadIdx.x; e < NO * NO * NC; e += 256) {
        float a = 0.f;
        #pragma unroll
        for (int k = 0; k < MT; ++k) {
            int i1 = st + k; i1 = (i1 < NI) ? i1 : (NI - 1);
            a += w1s[k] * Sb[(size_t)i1 * (NO * NO * NC) + e];
        }
        ob[e] = a;
    }
}

// ---------------------------------------------------------------------------
extern "C" void kernel_launch(void* const* d_in, const int* in_sizes, int n_in,
                              void* d_out, int out_size, void* d_ws, size_t ws_size,
                              hipStream_t stream) {
    (void)in_sizes; (void)n_in; (void)out_size;
    const float* img = (const float*)d_in[0];
    float* out = (float*)d_out;
    char* ws = (char*)d_ws;

    if (ws_size >= A1H_BYTES + A2_BYTES) {
        __half* A1h = (__half*)ws;
        float*  A2  = (float*)(ws + A1H_BYTES);
        k_p1<<<NB * NI * (NI / CH1), 256, 0, stream>>>(img, A1h);
        int p2b = (int)((P2_THREADS + 255) / 256);
        k_p2<<<p2b, 256, 0, stream>>>(A1h, A2);
        int p3b = (int)((P3_THREADS + 255) / 256);
        k_p3<<<p3b, 256, 0, stream>>>(A2, out);
    } else {
        float* S = (float*)ws;                       // 14.2 MB
        k_passA<<<NB * NI, 256, 0, stream>>>(img, S);
        k_passB<<<NB * NO, 256, 0, stream>>>(S, out);
    }
}

// Round 14
// 69.366 us; speedup vs baseline: 1.4050x; 1.0343x over previous
//
#include <hip/hip_runtime.h>
#include <hip/hip_fp16.h>

// Problem constants
#define NB 4      // batch
#define NI 160    // input spatial size (all 3 dims)
#define NO 43     // output spatial size: ceil(160/4)+3
#define NC 3      // channels
#define KS 7      // gaussian kernel size per axis
#define KPAD 3    // (KS-1)/2
#define MT 16     // stored taps per banded row (true max = 14)
#define CH 8      // rows per chunk (fallback)
#define CH1 4     // rows per chunk in k_p1
#define P1B 128   // k_p1 block size
#define NP 22     // o3 pairs (21 full + 1 half)

#define ROWF (NI * NC)            // 480 floats per input row
#define PROW 132                  // padded (o3,c) row: 129 -> 132 elems
#define PROW4 (PROW / 4)          // 33 groups of 4
#define LROW 484                  // LDS row stride (484 % 32 == 4)
#define SLICE (NO * NO * NC)

#define A1H_BYTES ((size_t)NB * NI * NI * PROW * 2)      // 27,033,600 (fp16)
#define A2_BYTES  ((size_t)NB * NI * NO * PROW * 4)      // 14,530,560 (fp32)
#define P2_THREADS ((size_t)NB * NI * NO * PROW4)        // 908,160
#define P3_THREADS ((size_t)NB * NO * NO * PROW4)        // 244,068

// ===========================================================================
// Compile-time weight tables (validated r8/r9/r12/r13, absmax <= 9.8e-4).
// New: wp[p][24][2] — union-window weights for o3 pair (2p, 2p+1), taps
// jp = j3[2p] .. jp+23. Taps outside a member's band (incl. j >= NI) are
// EXACTLY 0.0, so frame over-reach multiplies garbage by zero.
// ===========================================================================
struct __align__(16) Tables {
    float wa3[NO][20];      // 3440 B (kept for layout stability)
    float w1[NO][MT];       // 2752 B  banded 16-tap weights (p2/p3/fallback)
    float wp[NP][24][2];    // 4224 B  pair-union weights (k_p1)
    int   o1h[NO][MT];      // byte offsets, stride PROW*2 = 264   (p2)
    int   o0[NO][MT];       // byte offsets, stride NO*PROW*4      (p3)
    int   j3[NO];           // aligned window starts (multiples of 4)
    int   jlo[NO];          // band starts
};

constexpr double ctaylor(double r) {            // exp(r), r in [0, 1/16]
    double s = 1.0, term = 1.0;
    for (int n = 1; n <= 13; ++n) { term *= r / (double)n; s += term; }
    return s;
}
constexpr double cexp_neg(double x) {           // exp(x), x <= 0, |x| < 40
    double y = -x;
    int k = (int)(y * 16.0);
    double r = y - (double)k / 16.0;
    double e16 = ctaylor(1.0 / 16.0);
    double p = 1.0;
    for (int i = 0; i < k; ++i) p *= e16;
    return 1.0 / (p * ctaylor(r));
}
constexpr int cceil(double x)  { int c = (int)x; return ((double)c < x) ? c + 1 : c; }
constexpr int cfloor(double x) { int f = (int)x; return ((double)f > x) ? f - 1 : f; }
constexpr double cabsd(double x) { return x < 0 ? -x : x; }

constexpr double comp_w(int j, double sf, int ilo, int ihi, const double* g) {
    if (j >= NI || j < 0) return 0.0;           // taps at j>=NI are exactly 0
    double cw = 0.0;
    for (int t = 0; t < KS; ++t) {
        int i = j + KPAD - t;
        if (i >= ilo && i <= ihi) {
            double w = 1.0 - cabsd(sf - (double)i) * (43.0 / 160.0);
            if (w > 0.0) cw += g[t] * w;
        }
    }
    return cw;
}

struct Band { double sf; int ilo; int ihi; double wsum; };
constexpr Band bandof(int o) {
    const double inv_scale = 160.0 / 43.0;
    double sf = ((double)o + 0.5) * inv_scale - 0.5;
    int ilo = cceil(sf - inv_scale);  if (ilo < 0) ilo = 0;
    int ihi = cfloor(sf + inv_scale); if (ihi > NI - 1) ihi = NI - 1;
    double wsum = 0.0;
    for (int i = ilo; i <= ihi; ++i) {
        double w = 1.0 - cabsd(sf - (double)i) * (43.0 / 160.0);
        if (w > 0.0) wsum += w;
    }
    return {sf, ilo, ihi, wsum};
}

constexpr Tables make_tables() {
    Tables T{};
    double g[KS] = {};
    double gs = 0.0;
    const double sig = 0.44 * 4.0;
    for (int i = 0; i < KS; ++i) {
        double d = (double)i - 3.0;
        g[i] = cexp_neg(-(d * d) / (2.0 * sig * sig));
        gs += g[i];
    }
    for (int i = 0; i < KS; ++i) g[i] /= gs;

    for (int o = 0; o < NO; ++o) {
        Band B = bandof(o);
        int jlo = B.ilo - KPAD; if (jlo < 0) jlo = 0;
        int j0 = jlo & ~3;
        T.j3[o] = j0;
        T.jlo[o] = jlo;
        for (int m = 0; m < 20; ++m)
            T.wa3[o][m] = (float)(comp_w(j0 + m, B.sf, B.ilo, B.ihi, g) / B.wsum);
        for (int k = 0; k < MT; ++k) {
            int j = jlo + k;
            T.w1[o][k] = (float)(comp_w(j, B.sf, B.ilo, B.ihi, g) / B.wsum);
            int jc = (j < NI) ? j : (NI - 1);       // pad taps have w=0
            T.o1h[o][k] = jc * (PROW * 2);
            T.o0[o][k]  = jc * (NO * PROW * 4);
        }
    }
    // pair-union windows (frame = 24 taps from j3[2p]; j3 steps by {0,4})
    for (int p = 0; p < NP; ++p) {
        int oA = 2 * p, oB = 2 * p + 1;
        Band BA = bandof(oA);
        int jp = T.j3[oA];
        for (int k = 0; k < 24; ++k) {
            T.wp[p][k][0] = (float)(comp_w(jp + k, BA.sf, BA.ilo, BA.ihi, g) / BA.wsum);
            if (oB < NO) {
                Band BB = bandof(oB);
                T.wp[p][k][1] = (float)(comp_w(jp + k, BB.sf, BB.ilo, BB.ihi, g) / BB.wsum);
            } else {
                T.wp[p][k][1] = 0.0f;               // unpaired o3=42 tail
            }
        }
    }
    return T;
}

__constant__ Tables dT = make_tables();

struct __align__(8) h4 { __half2 lo, hi; };
union h2u { __half2 h; unsigned int u; };

// ---------------------------------------------------------------------------
// P1 (r14): contract i3 -> o3 into fp16 A1h, o3-PAIR per thread.
// Union window = 24 taps -> 18 ds_read_b128 for SIX outputs (-40% LDS reads
// vs r13). Outputs pack to 3 aligned dwords -> direct global stores
// (dword-granular, no hs tile, ONE barrier). 128 thr / 8.2 KB LDS.
// Loop-blocked accumulation keeps ~12 data floats live (low VGPR).
// ---------------------------------------------------------------------------
__global__ __launch_bounds__(P1B) void k_p1(
        const float* __restrict__ img, __half* __restrict__ A1h) {
    __shared__ __align__(16) float rows[CH1 * LROW + 64];  // 2000 f = 8 KB
    int t = threadIdx.x;
    int blk = blockIdx.x;                  // (b*160+i1)*40 + chunk

    const int p = t % NP, row = t / NP;    // valid when t < 88
    const bool has = (t < NP * CH1);

    // weight + window preload (constant mem; overlaps staging)
    float4 wq0, wq1, wq2, wq3, wq4, wq5, wq6, wq7, wq8, wq9, wq10, wq11;
    int jp = 0;
    if (has) {
        jp = dT.j3[2 * p];
        const float4* wpp = (const float4*)dT.wp[p];
        wq0 = wpp[0];  wq1 = wpp[1];  wq2 = wpp[2];  wq3 = wpp[3];
        wq4 = wpp[4];  wq5 = wpp[5];  wq6 = wpp[6];  wq7 = wpp[7];
        wq8 = wpp[8];  wq9 = wpp[9];  wq10 = wpp[10]; wq11 = wpp[11];
    }

    // stage 4 rows (480 float4, coalesced)
    const float4* src = (const float4*)(img + (size_t)blk * (CH1 * ROWF));
    for (int g = t; g < CH1 * ROWF / 4; g += P1B) {
        int r = g / 120, m = g % 120;
        *(float4*)(rows + r * LROW + 4 * m) = src[g];
    }
    if (t < 16) rows[(t >> 2) * LROW + ROWF + (t & 3)] = 0.f;   // row pads
    if (t >= 16 && t < 80) rows[CH1 * LROW + (t - 16)] = 0.f;   // tail slack
    __syncthreads();

    if (has) {
        const float4* dp = (const float4*)(rows + row * LROW + 3 * jp);
        float a0 = 0.f, a1 = 0.f, a2 = 0.f;    // o3 = 2p
        float b0 = 0.f, b1 = 0.f, b2 = 0.f;    // o3 = 2p+1
        // 6 iterations x 4 taps; weights float4 q covers taps {2q,2q+1} as
        // (wA,wB,wA,wB)
#define STEP(M, WQA, WQB) {                                                    \
            float4 v0 = dp[3*(M)], v1 = dp[3*(M)+1], v2 = dp[3*(M)+2];         \
            a0 += WQA.x * v0.x; a1 += WQA.x * v0.y; a2 += WQA.x * v0.z;        \
            b0 += WQA.y * v0.x; b1 += WQA.y * v0.y; b2 += WQA.y * v0.z;        \
            a0 += WQA.z * v0.w; a1 += WQA.z * v1.x; a2 += WQA.z * v1.y;        \
            b0 += WQA.w * v0.w; b1 += WQA.w * v1.x; b2 += WQA.w * v1.y;        \
            a0 += WQB.x * v1.z; a1 += WQB.x * v1.w; a2 += WQB.x * v2.x;        \
            b0 += WQB.y * v1.z; b1 += WQB.y * v1.w; b2 += WQB.y * v2.x;        \
            a0 += WQB.z * v2.y; a1 += WQB.z * v2.z; a2 += WQB.z * v2.w;        \
            b0 += WQB.w * v2.y; b1 += WQB.w * v2.z; b2 += WQB.w * v2.w;        \
        }
        STEP(0, wq0, wq1)  STEP(1, wq2, wq3)  STEP(2, wq4, wq5)
        STEP(3, wq6, wq7)  STEP(4, wq8, wq9)  STEP(5, wq10, wq11)
#undef STEP
        // pack 6 halves -> 3 dwords; dword-granular global store
        h2u c0, c1, c2;
        c0.h = __floats2half2_rn(a0, a1);
        c1.h = __floats2half2_rn(a2, b0);
        c2.h = __floats2half2_rn(b1, b2);
        unsigned int* dstu = (unsigned int*)A1h;
        size_t baseu = ((size_t)blk * CH1 + row) * (PROW / 2) + 3 * p;
        dstu[baseu] = c0.u; dstu[baseu + 1] = c1.u; dstu[baseu + 2] = c2.u;
    }
}

// Bijective XCD-chunked block swizzle (m204 form).
__device__ __forceinline__ int xcd_swz(int wg, int nwg) {
    int q = nwg >> 3, r = nwg & 7;
    int x = wg & 7, i = wg >> 3;
    return (x < r ? x * (q + 1) : r * (q + 1) + (x - r) * q) + i;
}

// ---------------------------------------------------------------------------
// P2: contract i2 -> o2.  A2[b][i1][o2][132] fp32. Thread per 4 cols;
// taps are 8B half4 loads from fp16 A1 (L2/L3-hot), converted in-register.
// (byte-identical to r13's passing k_p2)
// ---------------------------------------------------------------------------
__global__ __launch_bounds__(256) void k_p2(
        const __half* __restrict__ A1h, float* __restrict__ A2) {
    int blk = xcd_swz(blockIdx.x, gridDim.x);
    size_t idx = (size_t)blk * 256 + threadIdx.x;
    if (idx >= P2_THREADS) return;
    int ii = (int)idx;
    int col4 = ii % PROW4;
    int o2   = (ii / PROW4) % NO;
    int slab = ii / (PROW4 * NO);           // b*160 + i1
    const char* base = (const char*)A1h + ((size_t)slab * NI * PROW + col4 * 4) * 2;
    const float4* wv = (const float4*)dT.w1[o2];
    const int4*   ov = (const int4*)dT.o1h[o2];
    float4 w0 = wv[0], w1v = wv[1], w2 = wv[2], w3 = wv[3];
    int4   j0 = ov[0], j1 = ov[1], j2 = ov[2], j3 = ov[3];
    float4 a = {0.f, 0.f, 0.f, 0.f};
#define TAP4H(J, W) { h4 v = *(const h4*)(base + (unsigned)(J));               \
                      float2 f0 = __half22float2(v.lo);                        \
                      float2 f1 = __half22float2(v.hi);                        \
                      a.x += (W) * f0.x; a.y += (W) * f0.y;                    \
                      a.z += (W) * f1.x; a.w += (W) * f1.y; }
    TAP4H(j0.x, w0.x) TAP4H(j0.y, w0.y) TAP4H(j0.z, w0.z) TAP4H(j0.w, w0.w)
    TAP4H(j1.x, w1v.x) TAP4H(j1.y, w1v.y) TAP4H(j1.z, w1v.z) TAP4H(j1.w, w1v.w)
    TAP4H(j2.x, w2.x) TAP4H(j2.y, w2.y) TAP4H(j2.z, w2.z) TAP4H(j2.w, w2.w)
    TAP4H(j3.x, w3.x) TAP4H(j3.y, w3.y) TAP4H(j3.z, w3.z) TAP4H(j3.w, w3.w)
#undef TAP4H
    ((float4*)A2)[idx] = a;
}

// ---------------------------------------------------------------------------
// P3: contract i1 -> o1.  out[b][o1][o2][o3][c] (unpadded 129 cols).
// (byte-identical to r13's passing k_p3; masks pad cols >= 129)
// ---------------------------------------------------------------------------
__global__ __launch_bounds__(256) void k_p3(
        const float* __restrict__ A2, float* __restrict__ out) {
    int blk = xcd_swz(blockIdx.x, gridDim.x);
    size_t idx = (size_t)blk * 256 + threadIdx.x;
    if (idx >= P3_THREADS) return;
    int ii = (int)idx;
    int col4 = ii % PROW4;
    int o2   = (ii / PROW4) % NO;
    int o1   = (ii / (PROW4 * NO)) % NO;
    int b    = ii / (PROW4 * NO * NO);
    const char* base = (const char*)A2 +
        (((size_t)b * NI * NO + o2) * PROW + col4 * 4) * 4;
    const float4* wv = (const float4*)dT.w1[o1];
    const int4*   ov = (const int4*)dT.o0[o1];
    float4 w0 = wv[0], w1v = wv[1], w2 = wv[2], w3 = wv[3];
    int4   j0 = ov[0], j1 = ov[1], j2 = ov[2], j3 = ov[3];
    float4 a = {0.f, 0.f, 0.f, 0.f};
#define TAP4(J, W) { float4 v = *(const float4*)(base + (unsigned)(J)); \
                     a.x += (W) * v.x; a.y += (W) * v.y; a.z += (W) * v.z; a.w += (W) * v.w; }
    TAP4(j0.x, w0.x) TAP4(j0.y, w0.y) TAP4(j0.z, w0.z) TAP4(j0.w, w0.w)
    TAP4(j1.x, w1v.x) TAP4(j1.y, w1v.y) TAP4(j1.z, w1v.z) TAP4(j1.w, w1v.w)
    TAP4(j2.x, w2.x) TAP4(j2.y, w2.y) TAP4(j2.z, w2.z) TAP4(j2.w, w2.w)
    TAP4(j3.x, w3.x) TAP4(j3.y, w3.y) TAP4(j3.z, w3.z) TAP4(j3.w, w3.w)
#undef TAP4
    int tile = (b * NO + o1) * NO + o2;
    float* ob = out + (size_t)tile * (NO * NC) + col4 * 4;
    int col = col4 * 4;
    float av[4] = {a.x, a.y, a.z, a.w};
    #pragma unroll
    for (int e = 0; e < 4; ++e)
        if (col + e < NO * NC) ob[e] = av[e];
}

// ---------------------------------------------------------------------------
// FALLBACK (r1-structure, known-correct), fp32, setup-free.
// ---------------------------------------------------------------------------
__global__ __launch_bounds__(256) void k_passA(
        const float* __restrict__ img, float* __restrict__ S) {
    __shared__ float rows[CH * NI * NC];
    __shared__ float T[CH * NO * NC];
    __shared__ float acc[NO * NO * NC];
    __shared__ float w2[NO * MT];
    __shared__ int   s2[NO];
    int t = threadIdx.x;
    int blk = blockIdx.x;
    const float* src = img + (size_t)blk * (NI * NI * NC);
    for (int k = t; k < NO * MT; k += 256) w2[k] = ((const float*)dT.w1)[k];
    for (int k = t; k < NO; k += 256) s2[k] = dT.jlo[k];
    for (int k = t; k < NO * NO * NC; k += 256) acc[k] = 0.f;
    __syncthreads();
    for (int chunk = 0; chunk < NI / CH; ++chunk) {
        const float4* csrc = (const float4*)(src + (size_t)chunk * CH * NI * NC);
        for (int k = t; k < CH * NI * NC / 4; k += 256)
            ((float4*)rows)[k] = csrc[k];
        __syncthreads();
        for (int task = t; task < CH * NO; task += 256) {
            int ch = task / NO, o3 = task % NO;
            int st = s2[o3];
            const float* rp = rows + ch * NI * NC;
            float a0 = 0.f, a1 = 0.f, a2 = 0.f;
            #pragma unroll
            for (int k = 0; k < MT; ++k) {
                int j = st + k; j = (j < NI) ? j : (NI - 1);
                float w = w2[o3 * MT + k];
                a0 += w * rp[j * 3 + 0];
                a1 += w * rp[j * 3 + 1];
                a2 += w * rp[j * 3 + 2];
            }
            T[task * NC + 0] = a0;
            T[task * NC + 1] = a1;
            T[task * NC + 2] = a2;
        }
        __syncthreads();
        int i2base = chunk * CH;
        for (int task = t; task < NO * NO; task += 256) {
            int o2 = task / NO, o3 = task % NO;
            int st = s2[o2];
            int k0 = i2base - st;        k0 = (k0 > 0) ? k0 : 0;
            int k1 = i2base + CH - st;   k1 = (k1 < MT) ? k1 : MT;
            if (k1 > k0) {
                float a0 = 0.f, a1 = 0.f, a2 = 0.f;
                for (int k = k0; k < k1; ++k) {
                    float w = w2[o2 * MT + k];
                    int ch = st + k - i2base;
                    a0 += w * T[(ch * NO + o3) * NC + 0];
                    a1 += w * T[(ch * NO + o3) * NC + 1];
                    a2 += w * T[(ch * NO + o3) * NC + 2];
                }
                acc[task * NC + 0] += a0;
                acc[task * NC + 1] += a1;
                acc[task * NC + 2] += a2;
            }
        }
        __syncthreads();
    }
    float* Sp = S + (size_t)blk * (NO * NO * NC);
    for (int k = t; k < NO * NO * NC; k += 256) Sp[k] = acc[k];
}

__global__ __launch_bounds__(256) void k_passB(
        const float* __restrict__ S, float* __restrict__ out) {
    int blk = blockIdx.x;
    int b = blk / NO, o1 = blk % NO;
    __shared__ float w1s[MT];
    __shared__ int s1v;
    if (threadIdx.x < MT) w1s[threadIdx.x] = dT.w1[o1][threadIdx.x];
    if (threadIdx.x == 0) s1v = dT.jlo[o1];
    __syncthreads();
    const float* Sb = S + (size_t)b * NI * (NO * NO * NC);
    float* ob = out + (size_t)blk * (NO * NO * NC);
    int st = s1v;
    for (int e = threadIdx.x; e < NO * NO * NC; e += 256) {
        float a = 0.f;
        #pragma unroll
        for (int k = 0; k < MT; ++k) {
            int i1 = st + k; i1 = (i1 < NI) ? i1 : (NI - 1);
            a += w1s[k] * Sb[(size_t)i1 * (NO * NO * NC) + e];
        }
        ob[e] = a;
    }
}

// ---------------------------------------------------------------------------
extern "C" void kernel_launch(void* const* d_in, const int* in_sizes, int n_in,
                              void* d_out, int out_size, void* d_ws, size_t ws_size,
                              hipStream_t stream) {
    (void)in_sizes; (void)n_in; (void)out_size;
    const float* img = (const float*)d_in[0];
    float* out = (float*)d_out;
    char* ws = (char*)d_ws;

    if (ws_size >= A1H_BYTES + A2_BYTES) {
        __half* A1h = (__half*)ws;
        float*  A2  = (float*)(ws + A1H_BYTES);
        k_p1<<<NB * NI * (NI / CH1), P1B, 0, stream>>>(img, A1h);
        int p2b = (int)((P2_THREADS + 255) / 256);
        k_p2<<<p2b, 256, 0, stream>>>(A1h, A2);
        int p3b = (int)((P3_THREADS + 255) / 256);
        k_p3<<<p3b, 256, 0, stream>>>(A2, out);
    } else {
        float* S = (float*)ws;                       // 14.2 MB
        k_passA<<<NB * NI, 256, 0, stream>>>(img, S);
        k_passB<<<NB * NO, 256, 0, stream>>>(S, out);
    }
}

// Round 15
// 67.469 us; speedup vs baseline: 1.4445x; 1.0281x over previous
//
#include <hip/hip_runtime.h>
#include <hip/hip_fp16.h>

// Problem constants
#define NB 4      // batch
#define NI 160    // input spatial size (all 3 dims)
#define NO 43     // output spatial size: ceil(160/4)+3
#define NC 3      // channels
#define KS 7      // gaussian kernel size per axis
#define KPAD 3    // (KS-1)/2
#define MT 16     // stored taps per banded row (true max = 14)
#define CH 8      // rows per chunk (fallback)
#define CH1 4     // rows per chunk in k_p1
#define P1B 128   // k_p1 block size
#define NP 22     // pairs (21 full + 1 half) — shared by p1 (o3) and p2 (o2)

#define ROWF (NI * NC)            // 480 floats per input row
#define PROW 132                  // padded (o3,c) row: 129 -> 132 elems
#define PROW4 (PROW / 4)          // 33 groups of 4
#define LROW 484                  // LDS row stride (484 % 32 == 4)
#define SLICE (NO * NO * NC)

#define A1H_BYTES ((size_t)NB * NI * NI * PROW * 2)      // 27,033,600 (fp16)
#define A2H_BYTES ((size_t)NB * NI * NO * PROW * 2)      // 7,265,280  (fp16)
#define P2P_THREADS ((size_t)NB * NI * NP * PROW4)       // 464,640
#define P3_THREADS ((size_t)NB * NO * NO * PROW4)        // 244,068

// ===========================================================================
// Compile-time weight tables (wp pair-union validated in r14's p1; weights
// are axis-shared, so p2 reuses wp verbatim with its own offset stride).
// Taps outside a member's band (incl. j >= NI) are EXACTLY 0.0.
// ===========================================================================
struct __align__(16) Tables {
    float w1[NO][MT];       // banded 16-tap weights (p3 / fallback)
    float wp[NP][24][2];    // pair-union weights (p1 o3-pairs, p2 o2-pairs)
    int   o1hp[NP][24];     // byte offsets for p2 pair taps, stride PROW*2=264
    int   o0h[NO][MT];      // byte offsets for p3 taps, stride NO*PROW*2=11352
    int   j3[NO];           // aligned window starts (multiples of 4)
    int   jlo[NO];          // band starts
};

constexpr double ctaylor(double r) {            // exp(r), r in [0, 1/16]
    double s = 1.0, term = 1.0;
    for (int n = 1; n <= 13; ++n) { term *= r / (double)n; s += term; }
    return s;
}
constexpr double cexp_neg(double x) {           // exp(x), x <= 0, |x| < 40
    double y = -x;
    int k = (int)(y * 16.0);
    double r = y - (double)k / 16.0;
    double e16 = ctaylor(1.0 / 16.0);
    double p = 1.0;
    for (int i = 0; i < k; ++i) p *= e16;
    return 1.0 / (p * ctaylor(r));
}
constexpr int cceil(double x)  { int c = (int)x; return ((double)c < x) ? c + 1 : c; }
constexpr int cfloor(double x) { int f = (int)x; return ((double)f > x) ? f - 1 : f; }
constexpr double cabsd(double x) { return x < 0 ? -x : x; }

constexpr double comp_w(int j, double sf, int ilo, int ihi, const double* g) {
    if (j >= NI || j < 0) return 0.0;           // taps at j>=NI are exactly 0
    double cw = 0.0;
    for (int t = 0; t < KS; ++t) {
        int i = j + KPAD - t;
        if (i >= ilo && i <= ihi) {
            double w = 1.0 - cabsd(sf - (double)i) * (43.0 / 160.0);
            if (w > 0.0) cw += g[t] * w;
        }
    }
    return cw;
}

struct Band { double sf; int ilo; int ihi; double wsum; };
constexpr Band bandof(int o) {
    const double inv_scale = 160.0 / 43.0;
    double sf = ((double)o + 0.5) * inv_scale - 0.5;
    int ilo = cceil(sf - inv_scale);  if (ilo < 0) ilo = 0;
    int ihi = cfloor(sf + inv_scale); if (ihi > NI - 1) ihi = NI - 1;
    double wsum = 0.0;
    for (int i = ilo; i <= ihi; ++i) {
        double w = 1.0 - cabsd(sf - (double)i) * (43.0 / 160.0);
        if (w > 0.0) wsum += w;
    }
    return {sf, ilo, ihi, wsum};
}

constexpr Tables make_tables() {
    Tables T{};
    double g[KS] = {};
    double gs = 0.0;
    const double sig = 0.44 * 4.0;
    for (int i = 0; i < KS; ++i) {
        double d = (double)i - 3.0;
        g[i] = cexp_neg(-(d * d) / (2.0 * sig * sig));
        gs += g[i];
    }
    for (int i = 0; i < KS; ++i) g[i] /= gs;

    for (int o = 0; o < NO; ++o) {
        Band B = bandof(o);
        int jlo = B.ilo - KPAD; if (jlo < 0) jlo = 0;
        T.j3[o] = jlo & ~3;
        T.jlo[o] = jlo;
        for (int k = 0; k < MT; ++k) {
            int j = jlo + k;
            T.w1[o][k] = (float)(comp_w(j, B.sf, B.ilo, B.ihi, g) / B.wsum);
            int jc = (j < NI) ? j : (NI - 1);       // pad taps have w=0
            T.o0h[o][k] = jc * (NO * PROW * 2);     // fp16 A2 i1-stride
        }
    }
    // pair-union windows (frame = 24 taps from j3[2p])
    for (int p = 0; p < NP; ++p) {
        int oA = 2 * p, oB = 2 * p + 1;
        Band BA = bandof(oA);
        int jp = T.j3[oA];
        for (int k = 0; k < 24; ++k) {
            T.wp[p][k][0] = (float)(comp_w(jp + k, BA.sf, BA.ilo, BA.ihi, g) / BA.wsum);
            if (oB < NO) {
                Band BB = bandof(oB);
                T.wp[p][k][1] = (float)(comp_w(jp + k, BB.sf, BB.ilo, BB.ihi, g) / BB.wsum);
            } else {
                T.wp[p][k][1] = 0.0f;               // unpaired tail
            }
            int jc = (jp + k < NI) ? (jp + k) : (NI - 1);
            T.o1hp[p][k] = jc * (PROW * 2);         // fp16 A1 i2-stride
        }
    }
    return T;
}

__constant__ Tables dT = make_tables();

struct __align__(8) h4 { __half2 lo, hi; };
union h2u { __half2 h; unsigned int u; };

// ---------------------------------------------------------------------------
// P1 (byte-identical to r14's passing k_p1): contract i3 -> o3 into fp16 A1h,
// o3-pair per thread, direct dword-granular global stores, one barrier.
// ---------------------------------------------------------------------------
__global__ __launch_bounds__(P1B) void k_p1(
        const float* __restrict__ img, __half* __restrict__ A1h) {
    __shared__ __align__(16) float rows[CH1 * LROW + 64];  // 2000 f = 8 KB
    int t = threadIdx.x;
    int blk = blockIdx.x;                  // (b*160+i1)*40 + chunk

    const int p = t % NP, row = t / NP;    // valid when t < 88
    const bool has = (t < NP * CH1);

    float4 wq0, wq1, wq2, wq3, wq4, wq5, wq6, wq7, wq8, wq9, wq10, wq11;
    int jp = 0;
    if (has) {
        jp = dT.j3[2 * p];
        const float4* wpp = (const float4*)dT.wp[p];
        wq0 = wpp[0];  wq1 = wpp[1];  wq2 = wpp[2];  wq3 = wpp[3];
        wq4 = wpp[4];  wq5 = wpp[5];  wq6 = wpp[6];  wq7 = wpp[7];
        wq8 = wpp[8];  wq9 = wpp[9];  wq10 = wpp[10]; wq11 = wpp[11];
    }

    const float4* src = (const float4*)(img + (size_t)blk * (CH1 * ROWF));
    for (int g = t; g < CH1 * ROWF / 4; g += P1B) {
        int r = g / 120, m = g % 120;
        *(float4*)(rows + r * LROW + 4 * m) = src[g];
    }
    if (t < 16) rows[(t >> 2) * LROW + ROWF + (t & 3)] = 0.f;   // row pads
    if (t >= 16 && t < 80) rows[CH1 * LROW + (t - 16)] = 0.f;   // tail slack
    __syncthreads();

    if (has) {
        const float4* dp = (const float4*)(rows + row * LROW + 3 * jp);
        float a0 = 0.f, a1 = 0.f, a2 = 0.f;    // o3 = 2p
        float b0 = 0.f, b1 = 0.f, b2 = 0.f;    // o3 = 2p+1
#define STEP(M, WQA, WQB) {                                                    \
            float4 v0 = dp[3*(M)], v1 = dp[3*(M)+1], v2 = dp[3*(M)+2];         \
            a0 += WQA.x * v0.x; a1 += WQA.x * v0.y; a2 += WQA.x * v0.z;        \
            b0 += WQA.y * v0.x; b1 += WQA.y * v0.y; b2 += WQA.y * v0.z;        \
            a0 += WQA.z * v0.w; a1 += WQA.z * v1.x; a2 += WQA.z * v1.y;        \
            b0 += WQA.w * v0.w; b1 += WQA.w * v1.x; b2 += WQA.w * v1.y;        \
            a0 += WQB.x * v1.z; a1 += WQB.x * v1.w; a2 += WQB.x * v2.x;        \
            b0 += WQB.y * v1.z; b1 += WQB.y * v1.w; b2 += WQB.y * v2.x;        \
            a0 += WQB.z * v2.y; a1 += WQB.z * v2.z; a2 += WQB.z * v2.w;        \
            b0 += WQB.w * v2.y; b1 += WQB.w * v2.z; b2 += WQB.w * v2.w;        \
        }
        STEP(0, wq0, wq1)  STEP(1, wq2, wq3)  STEP(2, wq4, wq5)
        STEP(3, wq6, wq7)  STEP(4, wq8, wq9)  STEP(5, wq10, wq11)
#undef STEP
        h2u c0, c1, c2;
        c0.h = __floats2half2_rn(a0, a1);
        c1.h = __floats2half2_rn(a2, b0);
        c2.h = __floats2half2_rn(b1, b2);
        unsigned int* dstu = (unsigned int*)A1h;
        size_t baseu = ((size_t)blk * CH1 + row) * (PROW / 2) + 3 * p;
        dstu[baseu] = c0.u; dstu[baseu + 1] = c1.u; dstu[baseu + 2] = c2.u;
    }
}

// Bijective XCD-chunked block swizzle (m204 form).
__device__ __forceinline__ int xcd_swz(int wg, int nwg) {
    int q = nwg >> 3, r = nwg & 7;
    int x = wg & 7, i = wg >> 3;
    return (x < r ? x * (q + 1) : r * (q + 1) + (x - r) * q) + i;
}

// ---------------------------------------------------------------------------
// P2 (r15): contract i2 -> o2-PAIR per thread (union window, 24 taps, -25%
// tap loads), output fp16 A2h[b][i1][o2][132]. 8B h4 stores (dword-granular).
// ---------------------------------------------------------------------------
__global__ __launch_bounds__(256) void k_p2(
        const __half* __restrict__ A1h, __half* __restrict__ A2h) {
    int blk = xcd_swz(blockIdx.x, gridDim.x);
    size_t idx = (size_t)blk * 256 + threadIdx.x;
    if (idx >= P2P_THREADS) return;
    int ii = (int)idx;
    int col4 = ii % PROW4;
    int p    = (ii / PROW4) % NP;
    int slab = ii / (PROW4 * NP);           // b*160 + i1
    const char* base = (const char*)A1h + ((size_t)slab * NI * PROW + col4 * 4) * 2;
    const float4* wpp = (const float4*)dT.wp[p];
    const int4*   ot  = (const int4*)dT.o1hp[p];
    float4 wq0 = wpp[0], wq1 = wpp[1], wq2 = wpp[2],  wq3 = wpp[3];
    float4 wq4 = wpp[4], wq5 = wpp[5], wq6 = wpp[6],  wq7 = wpp[7];
    float4 wq8 = wpp[8], wq9 = wpp[9], wq10 = wpp[10], wq11 = wpp[11];
    int4 t0 = ot[0], t1 = ot[1], t2 = ot[2], t3 = ot[3], t4 = ot[4], t5 = ot[5];
    float4 a = {0.f,0.f,0.f,0.f}, b = a;
#define TP(J, WA, WB) { h4 v = *(const h4*)(base + (unsigned)(J));             \
        float2 f0 = __half22float2(v.lo), f1 = __half22float2(v.hi);           \
        a.x += (WA) * f0.x; a.y += (WA) * f0.y;                                \
        a.z += (WA) * f1.x; a.w += (WA) * f1.y;                                \
        b.x += (WB) * f0.x; b.y += (WB) * f0.y;                                \
        b.z += (WB) * f1.x; b.w += (WB) * f1.y; }
    TP(t0.x, wq0.x, wq0.y)  TP(t0.y, wq0.z, wq0.w)
    TP(t0.z, wq1.x, wq1.y)  TP(t0.w, wq1.z, wq1.w)
    TP(t1.x, wq2.x, wq2.y)  TP(t1.y, wq2.z, wq2.w)
    TP(t1.z, wq3.x, wq3.y)  TP(t1.w, wq3.z, wq3.w)
    TP(t2.x, wq4.x, wq4.y)  TP(t2.y, wq4.z, wq4.w)
    TP(t2.z, wq5.x, wq5.y)  TP(t2.w, wq5.z, wq5.w)
    TP(t3.x, wq6.x, wq6.y)  TP(t3.y, wq6.z, wq6.w)
    TP(t3.z, wq7.x, wq7.y)  TP(t3.w, wq7.z, wq7.w)
    TP(t4.x, wq8.x, wq8.y)  TP(t4.y, wq8.z, wq8.w)
    TP(t4.z, wq9.x, wq9.y)  TP(t4.w, wq9.z, wq9.w)
    TP(t5.x, wq10.x, wq10.y) TP(t5.y, wq10.z, wq10.w)
    TP(t5.z, wq11.x, wq11.y) TP(t5.w, wq11.z, wq11.w)
#undef TP
    h4* A2h4 = (h4*)A2h;
    size_t rbase = ((size_t)slab * NO + 2 * p) * PROW4 + col4;
    h4 ra; ra.lo = __floats2half2_rn(a.x, a.y); ra.hi = __floats2half2_rn(a.z, a.w);
    A2h4[rbase] = ra;
    if (2 * p + 1 < NO) {
        h4 rb; rb.lo = __floats2half2_rn(b.x, b.y); rb.hi = __floats2half2_rn(b.z, b.w);
        A2h4[rbase + PROW4] = rb;
    }
}

// ---------------------------------------------------------------------------
// P3 (r15): contract i1 -> o1 from fp16 A2h. out[b][o1][o2][o3][c] fp32
// (unpadded 129 cols, masked). Structure = r12's proven fp16-tap gather.
// ---------------------------------------------------------------------------
__global__ __launch_bounds__(256) void k_p3(
        const __half* __restrict__ A2h, float* __restrict__ out) {
    int blk = xcd_swz(blockIdx.x, gridDim.x);
    size_t idx = (size_t)blk * 256 + threadIdx.x;
    if (idx >= P3_THREADS) return;
    int ii = (int)idx;
    int col4 = ii % PROW4;
    int o2   = (ii / PROW4) % NO;
    int o1   = (ii / (PROW4 * NO)) % NO;
    int b    = ii / (PROW4 * NO * NO);
    const char* base = (const char*)A2h +
        (((size_t)b * NI * NO + o2) * PROW + col4 * 4) * 2;
    const float4* wv = (const float4*)dT.w1[o1];
    const int4*   ov = (const int4*)dT.o0h[o1];
    float4 w0 = wv[0], w1v = wv[1], w2 = wv[2], w3 = wv[3];
    int4   j0 = ov[0], j1 = ov[1], j2 = ov[2], j3 = ov[3];
    float4 a = {0.f, 0.f, 0.f, 0.f};
#define TAP4H(J, W) { h4 v = *(const h4*)(base + (unsigned)(J));               \
                      float2 f0 = __half22float2(v.lo);                        \
                      float2 f1 = __half22float2(v.hi);                        \
                      a.x += (W) * f0.x; a.y += (W) * f0.y;                    \
                      a.z += (W) * f1.x; a.w += (W) * f1.y; }
    TAP4H(j0.x, w0.x) TAP4H(j0.y, w0.y) TAP4H(j0.z, w0.z) TAP4H(j0.w, w0.w)
    TAP4H(j1.x, w1v.x) TAP4H(j1.y, w1v.y) TAP4H(j1.z, w1v.z) TAP4H(j1.w, w1v.w)
    TAP4H(j2.x, w2.x) TAP4H(j2.y, w2.y) TAP4H(j2.z, w2.z) TAP4H(j2.w, w2.w)
    TAP4H(j3.x, w3.x) TAP4H(j3.y, w3.y) TAP4H(j3.z, w3.z) TAP4H(j3.w, w3.w)
#undef TAP4H
    int tile = (b * NO + o1) * NO + o2;
    float* ob = out + (size_t)tile * (NO * NC) + col4 * 4;
    int col = col4 * 4;
    float av[4] = {a.x, a.y, a.z, a.w};
    #pragma unroll
    for (int e = 0; e < 4; ++e)
        if (col + e < NO * NC) ob[e] = av[e];
}

// ---------------------------------------------------------------------------
// FALLBACK (r1-structure, known-correct), fp32, setup-free.
// ---------------------------------------------------------------------------
__global__ __launch_bounds__(256) void k_passA(
        const float* __restrict__ img, float* __restrict__ S) {
    __shared__ float rows[CH * NI * NC];
    __shared__ float T[CH * NO * NC];
    __shared__ float acc[NO * NO * NC];
    __shared__ float w2[NO * MT];
    __shared__ int   s2[NO];
    int t = threadIdx.x;
    int blk = blockIdx.x;
    const float* src = img + (size_t)blk * (NI * NI * NC);
    for (int k = t; k < NO * MT; k += 256) w2[k] = ((const float*)dT.w1)[k];
    for (int k = t; k < NO; k += 256) s2[k] = dT.jlo[k];
    for (int k = t; k < NO * NO * NC; k += 256) acc[k] = 0.f;
    __syncthreads();
    for (int chunk = 0; chunk < NI / CH; ++chunk) {
        const float4* csrc = (const float4*)(src + (size_t)chunk * CH * NI * NC);
        for (int k = t; k < CH * NI * NC / 4; k += 256)
            ((float4*)rows)[k] = csrc[k];
        __syncthreads();
        for (int task = t; task < CH * NO; task += 256) {
            int ch = task / NO, o3 = task % NO;
            int st = s2[o3];
            const float* rp = rows + ch * NI * NC;
            float a0 = 0.f, a1 = 0.f, a2 = 0.f;
            #pragma unroll
            for (int k = 0; k < MT; ++k) {
                int j = st + k; j = (j < NI) ? j : (NI - 1);
                float w = w2[o3 * MT + k];
                a0 += w * rp[j * 3 + 0];
                a1 += w * rp[j * 3 + 1];
                a2 += w * rp[j * 3 + 2];
            }
            T[task * NC + 0] = a0;
            T[task * NC + 1] = a1;
            T[task * NC + 2] = a2;
        }
        __syncthreads();
        int i2base = chunk * CH;
        for (int task = t; task < NO * NO; task += 256) {
            int o2 = task / NO, o3 = task % NO;
            int st = s2[o2];
            int k0 = i2base - st;        k0 = (k0 > 0) ? k0 : 0;
            int k1 = i2base + CH - st;   k1 = (k1 < MT) ? k1 : MT;
            if (k1 > k0) {
                float a0 = 0.f, a1 = 0.f, a2 = 0.f;
                for (int k = k0; k < k1; ++k) {
                    float w = w2[o2 * MT + k];
                    int ch = st + k - i2base;
                    a0 += w * T[(ch * NO + o3) * NC + 0];
                    a1 += w * T[(ch * NO + o3) * NC + 1];
                    a2 += w * T[(ch * NO + o3) * NC + 2];
                }
                acc[task * NC + 0] += a0;
                acc[task * NC + 1] += a1;
                acc[task * NC + 2] += a2;
            }
        }
        __syncthreads();
    }
    float* Sp = S + (size_t)blk * (NO * NO * NC);
    for (int k = t; k < NO * NO * NC; k += 256) Sp[k] = acc[k];
}

__global__ __launch_bounds__(256) void k_passB(
        const float* __restrict__ S, float* __restrict__ out) {
    int blk = blockIdx.x;
    int b = blk / NO, o1 = blk % NO;
    __shared__ float w1s[MT];
    __shared__ int s1v;
    if (threadIdx.x < MT) w1s[threadIdx.x] = dT.w1[o1][threadIdx.x];
    if (threadIdx.x == 0) s1v = dT.jlo[o1];
    __syncthreads();
    const float* Sb = S + (size_t)b * NI * (NO * NO * NC);
    float* ob = out + (size_t)blk * (NO * NO * NC);
    int st = s1v;
    for (int e = threadIdx.x; e < NO * NO * NC; e += 256) {
        float a = 0.f;
        #pragma unroll
        for (int k = 0; k < MT; ++k) {
            int i1 = st + k; i1 = (i1 < NI) ? i1 : (NI - 1);
            a += w1s[k] * Sb[(size_t)i1 * (NO * NO * NC) + e];
        }
        ob[e] = a;
    }
}

// ---------------------------------------------------------------------------
extern "C" void kernel_launch(void* const* d_in, const int* in_sizes, int n_in,
                              void* d_out, int out_size, void* d_ws, size_t ws_size,
                              hipStream_t stream) {
    (void)in_sizes; (void)n_in; (void)out_size;
    const float* img = (const float*)d_in[0];
    float* out = (float*)d_out;
    char* ws = (char*)d_ws;

    if (ws_size >= A1H_BYTES + A2H_BYTES) {
        __half* A1h = (__half*)ws;
        __half* A2h = (__half*)(ws + A1H_BYTES);
        k_p1<<<NB * NI * (NI / CH1), P1B, 0, stream>>>(img, A1h);
        int p2b = (int)((P2P_THREADS + 255) / 256);
        k_p2<<<p2b, 256, 0, stream>>>(A1h, A2h);
        int p3b = (int)((P3_THREADS + 255) / 256);
        k_p3<<<p3b, 256, 0, stream>>>(A2h, out);
    } else {
        float* S = (float*)ws;                       // 14.2 MB
        k_passA<<<NB * NI, 256, 0, stream>>>(img, S);
        k_passB<<<NB * NO, 256, 0, stream>>>(S, out);
    }
}